// Round 12
// baseline (283.853 us; speedup 1.0000x reference)
//
#include <hip/hip_runtime.h>
#include <math.h>

#define N_NODES 100000
#define D 256
#define C 128
#define N_EDGES 3200000

#define BROWS 128                                // rows per bucket (b = row >> 7)
#define NBUCKET ((N_NODES + BROWS - 1) / BROWS)  // 782
#define CAP 4608                                 // bucket capacity (mean 4096 + 8 sigma)
#define EPB 8192                                 // edges per partition block
#define PBLOCKS ((N_EDGES + EPB - 1) / EPB)      // 391

typedef __attribute__((ext_vector_type(8))) short bf16x8;
typedef __attribute__((ext_vector_type(4))) float f32x4;

// ---------------------------------------------------------------------------
// helpers
// ---------------------------------------------------------------------------
__device__ __forceinline__ unsigned short f2bf(float f) {
  const unsigned int u = __float_as_uint(f);
  return (unsigned short)((u + 0x7fffu + ((u >> 16) & 1u)) >> 16);
}
__device__ __forceinline__ unsigned int pack_bf(float lo, float hi) {
  return (unsigned int)f2bf(lo) | ((unsigned int)f2bf(hi) << 16);
}
__device__ __forceinline__ float bflo(unsigned int u) {
  return __uint_as_float(u << 16);
}
__device__ __forceinline__ float bfhi(unsigned int u) {
  return __uint_as_float(u & 0xffff0000u);
}
__device__ __forceinline__ float selu1(float x) {
  const float scale = 1.0507009873554804934193349852946f;
  const float alpha = 1.6732632423543772848170429916717f;
  return x > 0.f ? scale * x : scale * alpha * (__expf(x) - 1.f);
}
// colval word: col in bits [31:15], bf16(val) sans sign (val>=0) in [14:0]
__device__ __forceinline__ unsigned int pack_rec(int col, float val) {
  return ((unsigned int)col << 15) | ((unsigned int)f2bf(val) & 0x7fffu);
}
__device__ __forceinline__ float rec_val(unsigned int r) {
  return __uint_as_float((r & 0x7fffu) << 16);
}
__device__ __forceinline__ bf16x8 packA_nt(const float* p) {
  const f32x4 a0 = __builtin_nontemporal_load(reinterpret_cast<const f32x4*>(p));
  const f32x4 a1 =
      __builtin_nontemporal_load(reinterpret_cast<const f32x4*>(p) + 1);
  union {
    unsigned int u[4];
    bf16x8 v;
  } af;
  af.u[0] = pack_bf(a0[0], a0[1]);
  af.u[1] = pack_bf(a0[2], a0[3]);
  af.u[2] = pack_bf(a1[0], a1[1]);
  af.u[3] = pack_bf(a1[2], a1[3]);
  return af.v;
}

// ---------------------------------------------------------------------------
// prep: WT[n][k] = bf16(W[k][n])  (64 KB) + zero gcur (no separate memset)
// ---------------------------------------------------------------------------
__global__ __launch_bounds__(256) void prep(const float* __restrict__ W,
                                            unsigned short* __restrict__ WT,
                                            int* __restrict__ gcur) {
  const int t = blockIdx.x * blockDim.x + threadIdx.x;  // 0..32767
  const int n = t >> 8;
  const int k = t & 255;
  WT[t] = f2bf(W[k * C + n]);
  if (t < NBUCKET) gcur[t] = 0;
}

// ---------------------------------------------------------------------------
// FUSED gemm + bucket-partition, 512-thr blocks, roles by bid&1.
//  - gemm role: h2 = bf16(X@W), 32 rows/wave, MFMA (r8-proven body).
//  - partition role: SINGLE LDS-atomic pass — hist atomicAdd's return value
//    IS the within-block offset (r11 did a redundant second atomic pass).
//    One global atomicAdd per (block,bucket) reserves a contiguous segment.
// ---------------------------------------------------------------------------
__global__ __launch_bounds__(512) void gemm_partition(
    const float* __restrict__ X, const unsigned short* __restrict__ WT,
    unsigned short* __restrict__ h2, const int* __restrict__ row,
    const int* __restrict__ col, const float* __restrict__ vals,
    int* __restrict__ gcur, uint2* __restrict__ recs) {
  __shared__ int hist[NBUCKET];
  __shared__ int sbase[NBUCKET];
  const int bid = blockIdx.x;
  const int tid = threadIdx.x;

  if ((bid & 1) == 0) {
    // ---------------- GEMM ----------------
    const int wid = (bid >> 1) * 8 + (tid >> 6);
    const int row0 = wid * 32;
    if (row0 >= N_NODES) return;
    const int lane = tid & 63;
    const int r = lane & 15;   // A row in tile / B col in frag
    const int kg = lane >> 4;  // k-group 0..3

    f32x4 acc[2][8];
#pragma unroll
    for (int g = 0; g < 2; ++g)
#pragma unroll
      for (int f = 0; f < 8; ++f) acc[g][f] = (f32x4){0.f, 0.f, 0.f, 0.f};

    const float* arow0 = X + (size_t)(row0 + r) * D + kg * 8;
    const float* arow1 = arow0 + 16 * D;
    for (int k0 = 0; k0 < D; k0 += 32) {
      const bf16x8 a0 = packA_nt(arow0 + k0);
      const bf16x8 a1 = packA_nt(arow1 + k0);
#pragma unroll
      for (int f = 0; f < 8; ++f) {
        const bf16x8 bf = *reinterpret_cast<const bf16x8*>(
            WT + (size_t)(f * 16 + r) * D + k0 + kg * 8);
        acc[0][f] =
            __builtin_amdgcn_mfma_f32_16x16x32_bf16(a0, bf, acc[0][f], 0, 0, 0);
        acc[1][f] =
            __builtin_amdgcn_mfma_f32_16x16x32_bf16(a1, bf, acc[1][f], 0, 0, 0);
      }
    }
    // C/D layout: col = lane&15, row = (lane>>4)*4 + reg  [m89-verified]
#pragma unroll
    for (int g = 0; g < 2; ++g)
#pragma unroll
      for (int f = 0; f < 8; ++f)
#pragma unroll
        for (int j = 0; j < 4; ++j)
          h2[(size_t)(row0 + g * 16 + kg * 4 + j) * C + f * 16 + r] =
              f2bf(acc[g][f][j]);
  } else {
    // ---------------- PARTITION (single atomic pass) ----------------
    const int pb = bid >> 1;  // 0..390
    const int e0 = pb * EPB;
    for (int i = tid; i < NBUCKET; i += 512) hist[i] = 0;
    __syncthreads();

    // pass 1: histogram; atomic return value = within-block offset.
    // stash r (17b) | off (<<17, off<8192) ; sentinel = all-ones.
    unsigned int stash[16];
#pragma unroll
    for (int k = 0; k < 16; ++k) {
      const int e = e0 + k * 512 + tid;
      unsigned int s = 0xFFFFFFFFu;
      if (e < N_EDGES) {
        const int r = __builtin_nontemporal_load(row + e);
        const int off = atomicAdd(&hist[r >> 7], 1);
        s = (unsigned int)r | ((unsigned int)off << 17);
      }
      stash[k] = s;
    }
    __syncthreads();
    // reserve one contiguous segment per (block,bucket)
    for (int b = tid; b < NBUCKET; b += 512) {
      const int h = hist[b];
      sbase[b] = h ? atomicAdd(&gcur[b], h) : 0;
    }
    __syncthreads();
    // pass 2: write records at reserved positions (no second atomic)
#pragma unroll
    for (int k = 0; k < 16; ++k) {
      const unsigned int s = stash[k];
      if (s == 0xFFFFFFFFu) continue;
      const int r = (int)(s & 0x1FFFFu);
      const int off = (int)(s >> 17);
      const int e = e0 + k * 512 + tid;
      const int c = __builtin_nontemporal_load(col + e);
      const float v = __builtin_nontemporal_load(vals + e);
      const int b = r >> 7;
      const int pos = sbase[b] + off;
      if (pos < CAP)
        recs[(size_t)b * CAP + pos] =
            make_uint2(pack_rec(c, v), r & (BROWS - 1));
    }
  }
}

// ---------------------------------------------------------------------------
// Sort-then-gather + skip/bias + SELU. One WG (512 thr) per bucket (128 rows).
// Phase 1: counting sort by local row — single LDS-atomic pass (offset from
//          atomic return), 7-step scan, scatter into LDS.
// Phase 2: wave-per-row register gather, 8-deep h2-gather ILP, fused epilogue.
// ---------------------------------------------------------------------------
__global__ __launch_bounds__(512) void sort_gather_selu(
    const int* __restrict__ gcur, const uint2* __restrict__ recs,
    const unsigned int* __restrict__ h2u, const float* __restrict__ skip,
    const float* __restrict__ bias, float* __restrict__ out) {
  __shared__ unsigned int sorted[CAP];  // 18.4 KB
  __shared__ int hist[BROWS];
  __shared__ int start[BROWS];  // inclusive scan of hist
  const int tid = threadIdx.x;
  const int b = blockIdx.x;

  int fill = gcur[b];
  fill = fill < CAP ? fill : CAP;

  if (tid < BROWS) hist[tid] = 0;
  __syncthreads();

  // pass 1: histogram; stash (colval, lr | off<<7)
  uint2 stash[9];  // ceil(4608/512)
  int nst = 0;
  const unsigned long long* rb64 =
      reinterpret_cast<const unsigned long long*>(recs + (size_t)b * CAP);
  for (int i = tid; i < fill; i += 512) {
    const unsigned long long rc = __builtin_nontemporal_load(rb64 + i);
    const unsigned int cv = (unsigned int)rc;
    const unsigned int lr = (unsigned int)(rc >> 32);
    const int off = atomicAdd(&hist[lr], 1);
    stash[nst] = make_uint2(cv, lr | ((unsigned int)off << 7));
    ++nst;
  }
  __syncthreads();

  // inclusive Hillis-Steele scan of hist -> start (128 elements, 7 steps)
  if (tid < BROWS) start[tid] = hist[tid];
  __syncthreads();
  for (int off = 1; off < BROWS; off <<= 1) {
    int t = 0;
    if (tid < BROWS && tid >= off) t = start[tid - off];
    __syncthreads();
    if (tid < BROWS) start[tid] += t;
    __syncthreads();
  }

  // pass 2: scatter colvals into row-contiguous order (no second atomic)
  for (int k = 0; k < nst; ++k) {
    const int lr = (int)(stash[k].y & 127u);
    const int off = (int)(stash[k].y >> 7);
    sorted[start[lr] - hist[lr] + off] = stash[k].x;
  }
  __syncthreads();

  // phase 2: wave wv handles local rows wv, wv+8, ...
  const int lane = tid & 63;
  const int wv = tid >> 6;
  for (int lr = wv; lr < BROWS; lr += 8) {
    const int grow = b * BROWS + lr;
    if (grow >= N_NODES) break;  // only trims tail of last bucket
    const int je = start[lr];
    int j = je - hist[lr];
    float ax = 0.f, ay = 0.f;
    for (; j + 7 < je; j += 8) {
      unsigned int cc[8], uu[8];
#pragma unroll
      for (int q = 0; q < 8; ++q) cc[q] = sorted[j + q];
#pragma unroll
      for (int q = 0; q < 8; ++q)
        uu[q] = h2u[(size_t)(cc[q] >> 15) * 64 + lane];
#pragma unroll
      for (int q = 0; q < 8; ++q) {
        ax = fmaf(rec_val(cc[q]), bflo(uu[q]), ax);
        ay = fmaf(rec_val(cc[q]), bfhi(uu[q]), ay);
      }
    }
    for (; j + 3 < je; j += 4) {
      unsigned int cc[4], uu[4];
#pragma unroll
      for (int q = 0; q < 4; ++q) cc[q] = sorted[j + q];
#pragma unroll
      for (int q = 0; q < 4; ++q)
        uu[q] = h2u[(size_t)(cc[q] >> 15) * 64 + lane];
#pragma unroll
      for (int q = 0; q < 4; ++q) {
        ax = fmaf(rec_val(cc[q]), bflo(uu[q]), ax);
        ay = fmaf(rec_val(cc[q]), bfhi(uu[q]), ay);
      }
    }
    for (; j < je; ++j) {
      const unsigned int cc = sorted[j];
      const unsigned int u = h2u[(size_t)(cc >> 15) * 64 + lane];
      ax = fmaf(rec_val(cc), bflo(u), ax);
      ay = fmaf(rec_val(cc), bfhi(u), ay);
    }
    // epilogue: out = selu(h*skip + agg + bias)
    const unsigned int hr = h2u[(size_t)grow * 64 + lane];
    const float2 sk = *reinterpret_cast<const float2*>(skip + lane * 2);
    const float2 bi = *reinterpret_cast<const float2*>(bias + lane * 2);
    const float ox = selu1(fmaf(bflo(hr), sk.x, ax) + bi.x);
    const float oy = selu1(fmaf(bfhi(hr), sk.y, ay) + bi.y);
    *reinterpret_cast<float2*>(out + (size_t)grow * C + lane * 2) =
        make_float2(ox, oy);
  }
}

extern "C" void kernel_launch(void* const* d_in, const int* in_sizes, int n_in,
                              void* d_out, int out_size, void* d_ws,
                              size_t ws_size, hipStream_t stream) {
  const float* features = (const float*)d_in[0];  // [n, 256]
  const int* adj_row = (const int*)d_in[1];       // [e]
  const int* adj_col = (const int*)d_in[2];       // [e]
  const float* adj_vals = (const float*)d_in[3];  // [e]
  const float* W = (const float*)d_in[4];         // [256, 128]
  const float* bias = (const float*)d_in[5];      // [128]
  const float* skip = (const float*)d_in[6];      // [128]
  float* out = (float*)d_out;                     // [n, 128]

  char* ws = (char*)d_ws;
  const size_t SZ_H2 = (size_t)N_NODES * C * 2;      // 25.6 MB
  const size_t OFF_RECS = (SZ_H2 + 255) & ~(size_t)255;
  const size_t SZ_RECS = (size_t)NBUCKET * CAP * 8;  // 28.8 MB
  const size_t OFF_GCUR = OFF_RECS + SZ_RECS;
  const size_t SZ_GCUR = (size_t)NBUCKET * 4;        // 3.1 KB
  const size_t OFF_WT = (OFF_GCUR + SZ_GCUR + 255) & ~(size_t)255;
  const size_t NEEDED = OFF_WT + (size_t)D * C * 2;  // ~54.5 MB

  if (ws_size < NEEDED) return;  // round-2 proved ws >= 115 MB

  unsigned short* h2 = (unsigned short*)ws;
  uint2* recs = (uint2*)(ws + OFF_RECS);
  int* gcur = (int*)(ws + OFF_GCUR);
  unsigned short* WT = (unsigned short*)(ws + OFF_WT);

  // 0) WT = bf16(W^T) + zero gcur
  prep<<<(D * C) / 256, 256, 0, stream>>>(W, WT, gcur);

  // 1) fused: h2 = bf16(X@W) (MFMA)  ||  bucket partition
  gemm_partition<<<2 * PBLOCKS, 512, 0, stream>>>(
      features, WT, h2, adj_row, adj_col, adj_vals, gcur, recs);

  // 2) per-bucket counting-sort + wave-per-row gather + skip/bias + SELU
  sort_gather_selu<<<NBUCKET, 512, 0, stream>>>(
      gcur, recs, (const unsigned int*)h2, skip, bias, out);
}